// Round 15
// baseline (364.715 us; speedup 1.0000x reference)
//
#include <hip/hip_runtime.h>
#include <math.h>

#define NN 20000
#define EE 100000
#define RR 4
#define HH 4
#define DD 64
#define FF 128
#define LL 2

typedef __attribute__((ext_vector_type(8))) short bf16x8;
typedef __attribute__((ext_vector_type(4))) float f32x4;

__device__ __forceinline__ ushort f2bf(float f) {
  uint u = __float_as_uint(f);
  u += 0x7FFFu + ((u >> 16) & 1u);
  return (ushort)(u >> 16);
}
__device__ __forceinline__ float bf2f(ushort h) {
  return __uint_as_float((uint)h << 16);
}

// ---------------------------------------------------------------------------
// Fused encoder + weight-prep. Blocks [0,5000): encoder; [5000,6059): prep.
__global__ __launch_bounds__(256) void enc_prep_kernel(
    const float* __restrict__ feat, const float* __restrict__ bet,
    const float* __restrict__ clo, const float* __restrict__ Wf,
    const float* __restrict__ bf, const float* __restrict__ Wc,
    const float* __restrict__ bc, float* __restrict__ x,
    ushort* __restrict__ xbf, const float* __restrict__ Wq,
    const float* __restrict__ bq, const float* __restrict__ Wk,
    const float* __restrict__ bk, const float* __restrict__ Wv,
    const float* __restrict__ bv, const float* __restrict__ Wp,
    ushort* __restrict__ mT, ushort* __restrict__ gT, float* __restrict__ cvec,
    float* __restrict__ gam) {
  const int t = threadIdx.x;
  if (blockIdx.x < 5000) {
    __shared__ float fs[4][FF];
    const int n0 = blockIdx.x * 4;
    for (int idx = t; idx < 4 * FF; idx += 256) {
      const int rr = idx >> 7, cc = idx & 127;
      const int n = n0 + rr;
      fs[rr][cc] = (n < NN) ? feat[(size_t)n * FF + cc] : 0.f;
    }
    __syncthreads();
    const int g = t >> 6, d = t & 63;
    const int n = n0 + g;
    if (n >= NN) return;
    float acc = bf[d] + bc[d] + bet[n] * Wc[d] + clo[n] * Wc[DD + d];
#pragma unroll 8
    for (int f = 0; f < FF; ++f) acc = fmaf(fs[g][f], Wf[f * DD + d], acc);
    x[(size_t)n * DD + d] = acc;
    xbf[(size_t)n * DD + d] = f2bf(acc);
    return;
  }
  const int idx = (blockIdx.x - 5000) * 256 + t;
  const int R1 = LL * RR * 272 * 64;  // 139264
  const int R2 = LL * 64 * 1024;      // 131072
  if (idx < R1) {
    const int lr = idx / (272 * 64);
    const int rem = idx % (272 * 64);
    const int col = rem >> 6, i = rem & 63;
    const float* wq = Wq + (size_t)lr * 64 * 256;
    const float* wk = Wk + (size_t)lr * 64 * 256;
    float v = 0.f;
    if (col < 256) {
      const int h = col >> 6, j = col & 63;
      const float* qa = wq + (size_t)i * 256 + h * 64;
      const float* kb = wk + (size_t)j * 256 + h * 64;
#pragma unroll 8
      for (int d = 0; d < 64; ++d) v = fmaf(qa[d], kb[d], v);
    } else if (col < 260) {
      const int h = col - 256;
      const float* qa = wq + (size_t)i * 256 + h * 64;
      const float* bb = bk + lr * 256 + h * 64;
#pragma unroll 8
      for (int d = 0; d < 64; ++d) v = fmaf(qa[d], bb[d], v);
    } else if (col < 264) {
      const int h = col - 260;
      const float* ka = wk + (size_t)i * 256 + h * 64;
      const float* bb = bq + lr * 256 + h * 64;
#pragma unroll 8
      for (int d = 0; d < 64; ++d) v = fmaf(ka[d], bb[d], v);
    }
    mT[idx] = f2bf(v);
  } else if (idx < R1 + R2) {
    const int id = idx - R1;  // = l*65536 + j*1024 + k
    const int lj = id >> 10;
    const int k = id & 1023;
    const int l = lj >> 6, j = lj & 63;
    const int r = k >> 8, h = (k >> 6) & 3, v_ = k & 63;
    const float* wv =
        Wv + (size_t)(l * RR + r) * 64 * 256 + (size_t)v_ * 256 + h * 64;
    const float* wp =
        Wp + (size_t)l * 65536 + (size_t)(r * 256 + h * 64) * 64 + j;
    float s = 0.f;
#pragma unroll 8
    for (int d = 0; d < 64; ++d) s = fmaf(wv[d], wp[d * 64], s);
    gT[id] = f2bf(s);
  } else if (idx < R1 + R2 + 512) {
    const int id = idx - R1 - R2;  // = l*256 + r*64 + j
    const int l = id >> 8, rj = id & 255;
    const int r = rj >> 6, j = rj & 63;
    const float* bb = bv + (l * RR + r) * 256;
    const float* wp = Wp + (size_t)l * 65536 + (size_t)(r * 256) * 64 + j;
    float s = 0.f;
    for (int q2 = 0; q2 < 256; ++q2) s = fmaf(bb[q2], wp[q2 * 64], s);
    cvec[id] = s;
  } else if (idx < R1 + R2 + 512 + 32) {
    const int id = idx - R1 - R2 - 512;  // = lr*4 + h
    const int lr = id >> 2, h = id & 3;
    const float* a = bq + lr * 256 + h * 64;
    const float* b2 = bk + lr * 256 + h * 64;
    float s = 0.f;
    for (int d = 0; d < 64; ++d) s = fmaf(a[d], b2[d], s);
    gam[id] = s;
  }
}

// ---------------------------------------------------------------------------
// CSR build
__global__ __launch_bounds__(256) void hist_kernel(
    const int* __restrict__ esrc, int* __restrict__ counts) {
  const int e = blockIdx.x * 256 + threadIdx.x;
  const int r = blockIdx.y;
  if (e < EE) atomicAdd(&counts[r * NN + esrc[(size_t)r * EE + e]], 1);
}

// Single-kernel exclusive scan: 1 block/relation, 1024 threads x 20 elems.
__global__ __launch_bounds__(1024) void scan_kernel(
    const int* __restrict__ counts, int* __restrict__ offs) {
  __shared__ int ts[1024];
  const int r = blockIdx.x, t = threadIdx.x;
  const int base = t * 20;
  int loc[20];
  int run = 0;
#pragma unroll
  for (int k = 0; k < 20; ++k) {
    const int i = base + k;
    const int v = (i < NN) ? counts[r * NN + i] : 0;
    run += v;
    loc[k] = run;
  }
  ts[t] = run;
  __syncthreads();
#pragma unroll
  for (int s = 1; s < 1024; s <<= 1) {
    const int add = (t >= s) ? ts[t - s] : 0;
    __syncthreads();
    ts[t] += add;
    __syncthreads();
  }
  const int prev = (t == 0) ? 0 : ts[t - 1];
#pragma unroll
  for (int k = 0; k < 20; ++k) {
    const int i = base + k;
    if (i < NN) offs[r * (NN + 1) + i + 1] = prev + loc[k];
  }
  if (t == 0) offs[r * (NN + 1)] = 0;
}

__global__ __launch_bounds__(256) void fill_kernel(
    const int* __restrict__ esrc, const int* __restrict__ etgt,
    const int* __restrict__ offs, int* __restrict__ cursor,
    int* __restrict__ csr) {
  const int e = blockIdx.x * 256 + threadIdx.x;
  const int r = blockIdx.y;
  if (e < EE) {
    const int s = esrc[(size_t)r * EE + e];
    const int pos = offs[r * (NN + 1) + s] + atomicAdd(&cursor[r * NN + s], 1);
    csr[(size_t)r * EE + pos] = etgt[(size_t)r * EE + e];
  }
}

// ---------------------------------------------------------------------------
// FUSED Y-GEMM + attention + projection.
// grid (1250, 4) = (16-node tile, relation). block 256 = 4 waves.
// Phase A (cooperative, one barrier): Y'[16][256] = x_tile @ M_r + wbeta
//          (bf16, LDS); wave w computes cols w*64..+63; wave 3 also alpha.
// Phase B (wave-private): wave w handles nodes m0+w*4..+3 (degree-averaging
//          within wave): max-free exp2 softmax, dual edge streams; attr row
//          overwrites own Y row in LDS.
// Phase C (wave-private, NO barrier): wave w projects its OWN 4 rows x all
//          64 cols. A-fragment rows replicated mod 4 (ys[w*4+(lo&3)]), so
//          C-row hi*4+i == node i for every hi; hi==0 lanes store.
__global__ __launch_bounds__(256) void yattn_kernel(
    const ushort* __restrict__ xbf, const int* __restrict__ offs4,
    const int* __restrict__ csr4, const float* __restrict__ nsi,
    const float* __restrict__ sw_l, const float* __restrict__ gam_l,
    const ushort* __restrict__ mT_l, const ushort* __restrict__ gT,
    float* __restrict__ partial) {
  __shared__ ushort ys[16][264];  // 8448 B
  __shared__ float alph[16][4];
  const int t = threadIdx.x;
  const int w = t >> 6, l = t & 63;
  const int hi = l >> 4, lo = l & 15;
  const int h = hi;
  const int m0 = blockIdx.x * 16;
  const int r = blockIdx.y;
  const ushort* mTr = mT_l + (size_t)r * 17408;  // [272][64]

  // ---- Phase A ----
  const ushort* arow = xbf + (size_t)(m0 + lo) * 64 + hi * 8;
  const bf16x8 a0 = *(const bf16x8*)(arow);
  const bf16x8 a1 = *(const bf16x8*)(arow + 32);
#pragma unroll
  for (int nt = 0; nt < 4; ++nt) {
    const int col0 = w * 64 + nt * 16;
    const ushort* brow = mTr + (size_t)(col0 + lo) * 64 + hi * 8;
    const bf16x8 b0 = *(const bf16x8*)(brow);
    const bf16x8 b1 = *(const bf16x8*)(brow + 32);
    f32x4 z = {0.f, 0.f, 0.f, 0.f};
    z = __builtin_amdgcn_mfma_f32_16x16x32_bf16(a0, b0, z, 0, 0, 0);
    z = __builtin_amdgcn_mfma_f32_16x16x32_bf16(a1, b1, z, 0, 0, 0);
    const int col = col0 + lo;
    const float wb = bf2f(mTr[(size_t)(260 + (col >> 6)) * 64 + (col & 63)]);
#pragma unroll
    for (int i = 0; i < 4; ++i) {
      ys[hi * 4 + i][col] = f2bf(z[i] + wb);
    }
  }
  if (w == 3) {  // alpha tile: walpha rows 256..259 of mT
    const ushort* brow = mTr + (size_t)(256 + lo) * 64 + hi * 8;
    const bf16x8 b0 = *(const bf16x8*)(brow);
    const bf16x8 b1 = *(const bf16x8*)(brow + 32);
    f32x4 z = {0.f, 0.f, 0.f, 0.f};
    z = __builtin_amdgcn_mfma_f32_16x16x32_bf16(a0, b0, z, 0, 0, 0);
    z = __builtin_amdgcn_mfma_f32_16x16x32_bf16(a1, b1, z, 0, 0, 0);
    if (lo < 4) {
#pragma unroll
      for (int i = 0; i < 4; ++i) alph[hi * 4 + i][lo] = z[i];
    }
  }
  __syncthreads();  // the only block-wide barrier (Phase A is uniform work)

  // ---- Phase B: 4 nodes per wave (wave-private rows) ----
  const int* offs = offs4 + r * (NN + 1);
  const int* csr = csr4 + (size_t)r * EE;
  const float swh = sw_l[h * RR + r];
  const float gamh = gam_l[r * 4 + h];
#pragma unroll
  for (int k = 0; k < 4; ++k) {
    const int idx = w * 4 + k;
    const int n = m0 + idx;
    const ushort4 yu = *(const ushort4*)&ys[idx][l * 4];
    const float y0 = bf2f(yu.x), y1 = bf2f(yu.y), y2 = bf2f(yu.z),
                y3 = bf2f(yu.w);
    const float c2 = 0.18033688f * nsi[n] * swh;
    const float ac2 = (alph[idx][h] + gamh) * c2;
    const int s0 = offs[n], e0 = offs[n + 1];
    float denA = 0.f, oA0 = 0.f, oA1 = 0.f, oA2 = 0.f, oA3 = 0.f;
    float denB = 0.f, oB0 = 0.f, oB1 = 0.f, oB2 = 0.f, oB3 = 0.f;
    int i = s0;
    for (; i + 1 < e0; i += 2) {
      const int tgA = __builtin_amdgcn_readfirstlane(csr[i]);
      const int tgB = __builtin_amdgcn_readfirstlane(csr[i + 1]);
      const ushort4 cxA = *(const ushort4*)(xbf + (size_t)tgA * 64 + lo * 4);
      const ushort4 cxB = *(const ushort4*)(xbf + (size_t)tgB * 64 + lo * 4);
      const float xA0 = bf2f(cxA.x), xA1 = bf2f(cxA.y), xA2 = bf2f(cxA.z),
                  xA3 = bf2f(cxA.w);
      const float xB0 = bf2f(cxB.x), xB1 = bf2f(cxB.y), xB2 = bf2f(cxB.z),
                  xB3 = bf2f(cxB.w);
      float dA = y0 * xA0;
      float dB = y0 * xB0;
      dA = fmaf(y1, xA1, dA);
      dB = fmaf(y1, xB1, dB);
      dA = fmaf(y2, xA2, dA);
      dB = fmaf(y2, xB2, dB);
      dA = fmaf(y3, xA3, dA);
      dB = fmaf(y3, xB3, dB);
#pragma unroll
      for (int dd = 1; dd < 16; dd <<= 1) {
        dA += __shfl_xor(dA, dd);
        dB += __shfl_xor(dB, dd);
      }
      const float ewA = __builtin_amdgcn_exp2f(fmaf(dA, c2, ac2));
      const float ewB = __builtin_amdgcn_exp2f(fmaf(dB, c2, ac2));
      denA += ewA;
      denB += ewB;
      oA0 = fmaf(ewA, xA0, oA0);
      oB0 = fmaf(ewB, xB0, oB0);
      oA1 = fmaf(ewA, xA1, oA1);
      oB1 = fmaf(ewB, xB1, oB1);
      oA2 = fmaf(ewA, xA2, oA2);
      oB2 = fmaf(ewB, xB2, oB2);
      oA3 = fmaf(ewA, xA3, oA3);
      oB3 = fmaf(ewB, xB3, oB3);
    }
    if (i < e0) {  // odd tail -> stream A
      const int tg = __builtin_amdgcn_readfirstlane(csr[i]);
      const ushort4 cx = *(const ushort4*)(xbf + (size_t)tg * 64 + lo * 4);
      const float x0 = bf2f(cx.x), x1 = bf2f(cx.y), x2 = bf2f(cx.z),
                  x3 = bf2f(cx.w);
      float d = y0 * x0;
      d = fmaf(y1, x1, d);
      d = fmaf(y2, x2, d);
      d = fmaf(y3, x3, d);
#pragma unroll
      for (int dd = 1; dd < 16; dd <<= 1) d += __shfl_xor(d, dd);
      const float ew = __builtin_amdgcn_exp2f(fmaf(d, c2, ac2));
      denA += ew;
      oA0 = fmaf(ew, x0, oA0);
      oA1 = fmaf(ew, x1, oA1);
      oA2 = fmaf(ew, x2, oA2);
      oA3 = fmaf(ew, x3, oA3);
    }
    const float inv = 1.f / (denA + denB + 1e-10f);
    ushort4 ou;
    ou.x = f2bf((oA0 + oB0) * inv);
    ou.y = f2bf((oA1 + oB1) * inv);
    ou.z = f2bf((oA2 + oB2) * inv);
    ou.w = f2bf((oA3 + oB3) * inv);
    *(ushort4*)&ys[idx][l * 4] = ou;  // own row: wave-private
  }
  // NO barrier: Phase C reads only this wave's own rows (same-wave lgkmcnt
  // ordering is compiler-enforced).

  // ---- Phase C: own 4 rows x 64 cols = ys_own @ G_r (K=256) ----
  // A-frag rows replicated mod 4 -> C row hi*4+i == node i for all hi.
  f32x4 acc[4] = {{0.f, 0.f, 0.f, 0.f},
                  {0.f, 0.f, 0.f, 0.f},
                  {0.f, 0.f, 0.f, 0.f},
                  {0.f, 0.f, 0.f, 0.f}};
#pragma unroll
  for (int ks = 0; ks < 8; ++ks) {
    const bf16x8 a = *(const bf16x8*)&ys[w * 4 + (lo & 3)][ks * 32 + hi * 8];
#pragma unroll
    for (int nt = 0; nt < 4; ++nt) {
      const bf16x8 bb = *(const bf16x8*)(gT + (size_t)(nt * 16 + lo) * 1024 +
                                         r * 256 + ks * 32 + hi * 8);
      acc[nt] = __builtin_amdgcn_mfma_f32_16x16x32_bf16(a, bb, acc[nt], 0, 0, 0);
    }
  }
  if (hi == 0) {
#pragma unroll
    for (int nt = 0; nt < 4; ++nt) {
#pragma unroll
      for (int i = 0; i < 4; ++i) {
        partial[((size_t)r * NN + m0 + w * 4 + i) * 64 + nt * 16 + lo] =
            acc[nt][i];
      }
    }
  }
}

// ---------------------------------------------------------------------------
// Final per-layer LN: sum 4 relation partials + cvec-mask + bias + residual,
// LayerNorm, write xout (+ bf16). grid 1250, block 256 = 4 waves x 4 nodes.
__global__ __launch_bounds__(256) void ln_kernel(
    const float* __restrict__ partial, const float* __restrict__ xin,
    const float* __restrict__ bp, const float* __restrict__ g,
    const float* __restrict__ b, const int* __restrict__ offs4,
    const float* __restrict__ cvec_l, float* __restrict__ xout,
    ushort* __restrict__ xbf_out) {
  const int t = threadIdx.x;
  const int w = t >> 6, l = t & 63;
  const int m0 = blockIdx.x * 16;
#pragma unroll
  for (int k = 0; k < 4; ++k) {
    const int n = m0 + w * 4 + k;
    float v = partial[((size_t)0 * NN + n) * 64 + l] +
              partial[((size_t)1 * NN + n) * 64 + l] +
              partial[((size_t)2 * NN + n) * 64 + l] +
              partial[((size_t)3 * NN + n) * 64 + l];
#pragma unroll
    for (int r = 0; r < 4; ++r) {
      const bool nz = offs4[r * (NN + 1) + n + 1] > offs4[r * (NN + 1) + n];
      v += nz ? cvec_l[r * 64 + l] : 0.f;
    }
    const float y = v + bp[l] + xin[(size_t)n * 64 + l];
    float s = y, s2 = y * y;
#pragma unroll
    for (int dd = 1; dd < 64; dd <<= 1) {
      s += __shfl_xor(s, dd);
      s2 += __shfl_xor(s2, dd);
    }
    const float mu = s * (1.f / 64.f);
    const float var = s2 * (1.f / 64.f) - mu * mu;
    const float xo = (y - mu) * rsqrtf(var + 1e-5f) * g[l] + b[l];
    xout[(size_t)n * 64 + l] = xo;
    if (xbf_out) xbf_out[(size_t)n * 64 + l] = f2bf(xo);
  }
}

// ---------------------------------------------------------------------------
extern "C" void kernel_launch(void* const* d_in, const int* in_sizes, int n_in,
                              void* d_out, int out_size, void* d_ws,
                              size_t ws_size, hipStream_t stream) {
  const float* feat = (const float*)d_in[1];
  const float* bet = (const float*)d_in[2];
  const float* clo = (const float*)d_in[3];
  const float* nsi = (const float*)d_in[4];
  const int* esrc = (const int*)d_in[5];
  const int* etgt = (const int*)d_in[6];
  const float* Wf = (const float*)d_in[7];
  const float* bf = (const float*)d_in[8];
  const float* Wc = (const float*)d_in[9];
  const float* bc = (const float*)d_in[10];
  const float* Wq = (const float*)d_in[11];
  const float* bq = (const float*)d_in[12];
  const float* Wk = (const float*)d_in[13];
  const float* bk = (const float*)d_in[14];
  const float* Wv = (const float*)d_in[15];
  const float* bv = (const float*)d_in[16];
  const float* Wp = (const float*)d_in[17];
  const float* bp = (const float*)d_in[18];
  const float* sw = (const float*)d_in[19];
  const float* lng = (const float*)d_in[20];
  const float* lnb = (const float*)d_in[21];
  float* out = (float*)d_out;

  char* base = (char*)d_ws;
  size_t off = 0;
  auto alloc = [&](size_t bytes) {
    void* p = base + off;
    off += (bytes + 255) & ~(size_t)255;
    return p;
  };
  float* xa = (float*)alloc((size_t)NN * DD * 4);     // 5.12 MB
  float* xb = (float*)alloc((size_t)NN * DD * 4);     // 5.12 MB
  ushort* xbf = (ushort*)alloc((size_t)NN * DD * 2);  // 2.56 MB
  float* partial = (float*)alloc((size_t)RR * NN * 64 * 4);     // 20.48 MB
  ushort* mT = (ushort*)alloc((size_t)LL * RR * 272 * 64 * 2);  // 557 KB
  ushort* gT = (ushort*)alloc((size_t)LL * 64 * 1024 * 2);      // 262 KB
  float* cvec = (float*)alloc((size_t)LL * RR * 64 * 4);        // 2 KB
  float* gam = (float*)alloc((size_t)LL * RR * HH * 4);         // 128 B
  int* counts = (int*)alloc((size_t)RR * NN * 4);
  int* offsb = (int*)alloc((size_t)RR * (NN + 1) * 4);
  int* csr = (int*)alloc((size_t)RR * EE * 4);
  (void)ws_size;

  // ---- CSR build ----
  hipMemsetAsync(counts, 0, (size_t)RR * NN * 4, stream);
  {
    dim3 gg((EE + 255) / 256, RR);
    hipLaunchKernelGGL(hist_kernel, gg, dim3(256), 0, stream, esrc, counts);
  }
  hipLaunchKernelGGL(scan_kernel, dim3(RR), dim3(1024), 0, stream, counts,
                     offsb);
  hipMemsetAsync(counts, 0, (size_t)RR * NN * 4, stream);  // reuse as cursor
  {
    dim3 gg((EE + 255) / 256, RR);
    hipLaunchKernelGGL(fill_kernel, gg, dim3(256), 0, stream, esrc, etgt, offsb,
                       counts, csr);
  }

  // ---- fused encoder + weight prep ----
  hipLaunchKernelGGL(enc_prep_kernel, dim3(6059), dim3(256), 0, stream, feat,
                     bet, clo, Wf, bf, Wc, bc, xa, xbf, Wq, bq, Wk, bk, Wv, bv,
                     Wp, mT, gT, cvec, gam);

  for (int l = 0; l < LL; ++l) {
    const float* xin = (l == 0) ? xa : xb;
    float* xout = (l == LL - 1) ? out : xb;
    ushort* xbf_next = (l == LL - 1) ? (ushort*)nullptr : xbf;
    hipLaunchKernelGGL(yattn_kernel, dim3(NN / 16, RR), dim3(256), 0, stream,
                       xbf, offsb, csr, nsi, sw + l * HH * RR, gam + l * 16,
                       mT + (size_t)l * RR * 17408, gT + (size_t)l * 65536,
                       partial);
    hipLaunchKernelGGL(ln_kernel, dim3(NN / 16), dim3(256), 0, stream, partial,
                       xin, bp + l * 64, lng + l * 64, lnb + l * 64, offsb,
                       cvec + l * 256, xout, xbf_next);
  }
}

// Round 16
// 265.805 us; speedup vs baseline: 1.3721x; 1.3721x over previous
//
#include <hip/hip_runtime.h>
#include <math.h>

#define NN 20000
#define EE 100000
#define RR 4
#define HH 4
#define DD 64
#define FF 128
#define LL 2

typedef __attribute__((ext_vector_type(8))) short bf16x8;
typedef __attribute__((ext_vector_type(4))) float f32x4;

__device__ __forceinline__ ushort f2bf(float f) {
  uint u = __float_as_uint(f);
  u += 0x7FFFu + ((u >> 16) & 1u);
  return (ushort)(u >> 16);
}
__device__ __forceinline__ float bf2f(ushort h) {
  return __uint_as_float((uint)h << 16);
}

// ---------------------------------------------------------------------------
// Fused encoder + weight-prep + edge histogram.
// Blocks [0,5000): encoder; [5000,6059): prep; [6059,7623): hist.
__global__ __launch_bounds__(256) void enc_prep_kernel(
    const float* __restrict__ feat, const float* __restrict__ bet,
    const float* __restrict__ clo, const float* __restrict__ Wf,
    const float* __restrict__ bf, const float* __restrict__ Wc,
    const float* __restrict__ bc, float* __restrict__ x,
    ushort* __restrict__ xbf, const float* __restrict__ Wq,
    const float* __restrict__ bq, const float* __restrict__ Wk,
    const float* __restrict__ bk, const float* __restrict__ Wv,
    const float* __restrict__ bv, const float* __restrict__ Wp,
    ushort* __restrict__ mT, ushort* __restrict__ gT, float* __restrict__ cvec,
    float* __restrict__ gam, const int* __restrict__ esrc,
    int* __restrict__ counts) {
  const int t = threadIdx.x;
  if (blockIdx.x >= 6059) {  // ---- hist ----
    const int gid = (blockIdx.x - 6059) * 256 + t;
    if (gid < RR * EE) {
      const int r = gid / EE;
      atomicAdd(&counts[r * NN + esrc[gid]], 1);
    }
    return;
  }
  if (blockIdx.x < 5000) {  // ---- encoder ----
    __shared__ float fs[4][FF];
    const int n0 = blockIdx.x * 4;
    for (int idx = t; idx < 4 * FF; idx += 256) {
      const int rr = idx >> 7, cc = idx & 127;
      const int n = n0 + rr;
      fs[rr][cc] = (n < NN) ? feat[(size_t)n * FF + cc] : 0.f;
    }
    __syncthreads();
    const int g = t >> 6, d = t & 63;
    const int n = n0 + g;
    if (n >= NN) return;
    float acc = bf[d] + bc[d] + bet[n] * Wc[d] + clo[n] * Wc[DD + d];
#pragma unroll 8
    for (int f = 0; f < FF; ++f) acc = fmaf(fs[g][f], Wf[f * DD + d], acc);
    x[(size_t)n * DD + d] = acc;
    xbf[(size_t)n * DD + d] = f2bf(acc);
    return;
  }
  const int idx = (blockIdx.x - 5000) * 256 + t;
  const int R1 = LL * RR * 272 * 64;  // 139264
  const int R2 = LL * 64 * 1024;      // 131072
  if (idx < R1) {
    const int lr = idx / (272 * 64);
    const int rem = idx % (272 * 64);
    const int col = rem >> 6, i = rem & 63;
    const float* wq = Wq + (size_t)lr * 64 * 256;
    const float* wk = Wk + (size_t)lr * 64 * 256;
    float v = 0.f;
    if (col < 256) {
      const int h = col >> 6, j = col & 63;
      const float* qa = wq + (size_t)i * 256 + h * 64;
      const float* kb = wk + (size_t)j * 256 + h * 64;
#pragma unroll 8
      for (int d = 0; d < 64; ++d) v = fmaf(qa[d], kb[d], v);
    } else if (col < 260) {
      const int h = col - 256;
      const float* qa = wq + (size_t)i * 256 + h * 64;
      const float* bb = bk + lr * 256 + h * 64;
#pragma unroll 8
      for (int d = 0; d < 64; ++d) v = fmaf(qa[d], bb[d], v);
    } else if (col < 264) {
      const int h = col - 260;
      const float* ka = wk + (size_t)i * 256 + h * 64;
      const float* bb = bq + lr * 256 + h * 64;
#pragma unroll 8
      for (int d = 0; d < 64; ++d) v = fmaf(ka[d], bb[d], v);
    }
    mT[idx] = f2bf(v);
  } else if (idx < R1 + R2) {
    const int id = idx - R1;  // = l*65536 + j*1024 + k
    const int lj = id >> 10;
    const int k = id & 1023;
    const int l = lj >> 6, j = lj & 63;
    const int r = k >> 8, h = (k >> 6) & 3, v_ = k & 63;
    const float* wv =
        Wv + (size_t)(l * RR + r) * 64 * 256 + (size_t)v_ * 256 + h * 64;
    const float* wp =
        Wp + (size_t)l * 65536 + (size_t)(r * 256 + h * 64) * 64 + j;
    float s = 0.f;
#pragma unroll 8
    for (int d = 0; d < 64; ++d) s = fmaf(wv[d], wp[d * 64], s);
    gT[id] = f2bf(s);
  } else if (idx < R1 + R2 + 512) {
    const int id = idx - R1 - R2;  // = l*256 + r*64 + j
    const int l = id >> 8, rj = id & 255;
    const int r = rj >> 6, j = rj & 63;
    const float* bb = bv + (l * RR + r) * 256;
    const float* wp = Wp + (size_t)l * 65536 + (size_t)(r * 256) * 64 + j;
    float s = 0.f;
    for (int q2 = 0; q2 < 256; ++q2) s = fmaf(bb[q2], wp[q2 * 64], s);
    cvec[id] = s;
  } else if (idx < R1 + R2 + 512 + 32) {
    const int id = idx - R1 - R2 - 512;  // = lr*4 + h
    const int lr = id >> 2, h = id & 3;
    const float* a = bq + lr * 256 + h * 64;
    const float* b2 = bk + lr * 256 + h * 64;
    float s = 0.f;
    for (int d = 0; d < 64; ++d) s = fmaf(a[d], b2[d], s);
    gam[id] = s;
  }
}

// ---------------------------------------------------------------------------
// Exclusive scan (1 block/relation, 1024 x 20); also zeroes counts -> cursor.
__global__ __launch_bounds__(1024) void scan_kernel(
    int* __restrict__ counts, int* __restrict__ offs) {
  __shared__ int ts[1024];
  const int r = blockIdx.x, t = threadIdx.x;
  const int base = t * 20;
  int loc[20];
  int run = 0;
#pragma unroll
  for (int k = 0; k < 20; ++k) {
    const int i = base + k;
    const int v = (i < NN) ? counts[r * NN + i] : 0;
    if (i < NN) counts[r * NN + i] = 0;  // becomes fill cursor
    run += v;
    loc[k] = run;
  }
  ts[t] = run;
  __syncthreads();
#pragma unroll
  for (int s = 1; s < 1024; s <<= 1) {
    const int add = (t >= s) ? ts[t - s] : 0;
    __syncthreads();
    ts[t] += add;
    __syncthreads();
  }
  const int prev = (t == 0) ? 0 : ts[t - 1];
#pragma unroll
  for (int k = 0; k < 20; ++k) {
    const int i = base + k;
    if (i < NN) offs[r * (NN + 1) + i + 1] = prev + loc[k];
  }
  if (t == 0) offs[r * (NN + 1)] = 0;
}

__global__ __launch_bounds__(256) void fill_kernel(
    const int* __restrict__ esrc, const int* __restrict__ etgt,
    const int* __restrict__ offs, int* __restrict__ cursor,
    int* __restrict__ csr) {
  const int e = blockIdx.x * 256 + threadIdx.x;
  const int r = blockIdx.y;
  if (e < EE) {
    const int s = esrc[(size_t)r * EE + e];
    const int pos = offs[r * (NN + 1) + s] + atomicAdd(&cursor[r * NN + s], 1);
    csr[(size_t)r * EE + pos] = etgt[(size_t)r * EE + e];
  }
}

// ---------------------------------------------------------------------------
// FUSED Y-GEMM + attention + projection. grid (625, 4) = (32-node tile, rel).
// block 256 = 4 waves.
// Phase A (one barrier): Y'[32][256] = x_tile @ M_r + wbeta; wave w computes
//          cols w*64..+63 for both 16-row groups; wave 3 also alpha[32][4].
// Phase B (wave-private): wave w handles 8 nodes m0+w*8..+7 (degree
//          averaging); attr row overwrites own Y row in LDS.
// Phase C: gT B-frags PREFETCHED before the barrier (latency hides under the
//          straggler wait); wave w projects cols w*16..+15 of all 32 rows
//          (16 MFMAs, K=256); writes f32 partial[r][n][64].
__global__ __launch_bounds__(256) void yattn_kernel(
    const ushort* __restrict__ xbf, const int* __restrict__ offs4,
    const int* __restrict__ csr4, const float* __restrict__ nsi,
    const float* __restrict__ sw_l, const float* __restrict__ gam_l,
    const ushort* __restrict__ mT_l, const ushort* __restrict__ gT,
    float* __restrict__ partial) {
  __shared__ ushort ys[32][264];  // 16.9 KB
  __shared__ float alph[32][4];
  const int t = threadIdx.x;
  const int w = t >> 6, l = t & 63;
  const int hi = l >> 4, lo = l & 15;
  const int h = hi;
  const int m0 = blockIdx.x * 32;
  const int r = blockIdx.y;
  const ushort* mTr = mT_l + (size_t)r * 17408;  // [272][64]

  // ---- Phase A: two 16-row groups ----
  const ushort* arow0 = xbf + (size_t)(m0 + lo) * 64 + hi * 8;
  const ushort* arow1 = xbf + (size_t)(m0 + 16 + lo) * 64 + hi * 8;
  const bf16x8 a00 = *(const bf16x8*)(arow0);
  const bf16x8 a01 = *(const bf16x8*)(arow0 + 32);
  const bf16x8 a10 = *(const bf16x8*)(arow1);
  const bf16x8 a11 = *(const bf16x8*)(arow1 + 32);
#pragma unroll
  for (int nt = 0; nt < 4; ++nt) {
    const int col0 = w * 64 + nt * 16;
    const ushort* brow = mTr + (size_t)(col0 + lo) * 64 + hi * 8;
    const bf16x8 b0 = *(const bf16x8*)(brow);
    const bf16x8 b1 = *(const bf16x8*)(brow + 32);
    f32x4 z0 = {0.f, 0.f, 0.f, 0.f};
    z0 = __builtin_amdgcn_mfma_f32_16x16x32_bf16(a00, b0, z0, 0, 0, 0);
    z0 = __builtin_amdgcn_mfma_f32_16x16x32_bf16(a01, b1, z0, 0, 0, 0);
    f32x4 z1 = {0.f, 0.f, 0.f, 0.f};
    z1 = __builtin_amdgcn_mfma_f32_16x16x32_bf16(a10, b0, z1, 0, 0, 0);
    z1 = __builtin_amdgcn_mfma_f32_16x16x32_bf16(a11, b1, z1, 0, 0, 0);
    const int col = col0 + lo;
    const float wb = bf2f(mTr[(size_t)(260 + (col >> 6)) * 64 + (col & 63)]);
#pragma unroll
    for (int i = 0; i < 4; ++i) {
      ys[hi * 4 + i][col] = f2bf(z0[i] + wb);
      ys[16 + hi * 4 + i][col] = f2bf(z1[i] + wb);
    }
  }
  if (w == 3) {  // alpha tiles: walpha rows 256..259 of mT
    const ushort* brow = mTr + (size_t)(256 + lo) * 64 + hi * 8;
    const bf16x8 b0 = *(const bf16x8*)(brow);
    const bf16x8 b1 = *(const bf16x8*)(brow + 32);
    f32x4 z0 = {0.f, 0.f, 0.f, 0.f};
    z0 = __builtin_amdgcn_mfma_f32_16x16x32_bf16(a00, b0, z0, 0, 0, 0);
    z0 = __builtin_amdgcn_mfma_f32_16x16x32_bf16(a01, b1, z0, 0, 0, 0);
    f32x4 z1 = {0.f, 0.f, 0.f, 0.f};
    z1 = __builtin_amdgcn_mfma_f32_16x16x32_bf16(a10, b0, z1, 0, 0, 0);
    z1 = __builtin_amdgcn_mfma_f32_16x16x32_bf16(a11, b1, z1, 0, 0, 0);
    if (lo < 4) {
#pragma unroll
      for (int i = 0; i < 4; ++i) {
        alph[hi * 4 + i][lo] = z0[i];
        alph[16 + hi * 4 + i][lo] = z1[i];
      }
    }
  }
  __syncthreads();

  // ---- Phase B: 8 nodes per wave (wave-private rows) ----
  const int* offs = offs4 + r * (NN + 1);
  const int* csr = csr4 + (size_t)r * EE;
  const float swh = sw_l[h * RR + r];
  const float gamh = gam_l[r * 4 + h];
  for (int k = 0; k < 8; ++k) {
    const int idx = w * 8 + k;
    const int n = m0 + idx;
    const ushort4 yu = *(const ushort4*)&ys[idx][l * 4];
    const float y0 = bf2f(yu.x), y1 = bf2f(yu.y), y2 = bf2f(yu.z),
                y3 = bf2f(yu.w);
    const float c2 = 0.18033688f * nsi[n] * swh;
    const float ac2 = (alph[idx][h] + gamh) * c2;
    const int s0 = offs[n], e0 = offs[n + 1];
    float denA = 0.f, oA0 = 0.f, oA1 = 0.f, oA2 = 0.f, oA3 = 0.f;
    float denB = 0.f, oB0 = 0.f, oB1 = 0.f, oB2 = 0.f, oB3 = 0.f;
    int i = s0;
    for (; i + 1 < e0; i += 2) {
      const int tgA = __builtin_amdgcn_readfirstlane(csr[i]);
      const int tgB = __builtin_amdgcn_readfirstlane(csr[i + 1]);
      const ushort4 cxA = *(const ushort4*)(xbf + (size_t)tgA * 64 + lo * 4);
      const ushort4 cxB = *(const ushort4*)(xbf + (size_t)tgB * 64 + lo * 4);
      const float xA0 = bf2f(cxA.x), xA1 = bf2f(cxA.y), xA2 = bf2f(cxA.z),
                  xA3 = bf2f(cxA.w);
      const float xB0 = bf2f(cxB.x), xB1 = bf2f(cxB.y), xB2 = bf2f(cxB.z),
                  xB3 = bf2f(cxB.w);
      float dA = y0 * xA0;
      float dB = y0 * xB0;
      dA = fmaf(y1, xA1, dA);
      dB = fmaf(y1, xB1, dB);
      dA = fmaf(y2, xA2, dA);
      dB = fmaf(y2, xB2, dB);
      dA = fmaf(y3, xA3, dA);
      dB = fmaf(y3, xB3, dB);
#pragma unroll
      for (int dd = 1; dd < 16; dd <<= 1) {
        dA += __shfl_xor(dA, dd);
        dB += __shfl_xor(dB, dd);
      }
      const float ewA = __builtin_amdgcn_exp2f(fmaf(dA, c2, ac2));
      const float ewB = __builtin_amdgcn_exp2f(fmaf(dB, c2, ac2));
      denA += ewA;
      denB += ewB;
      oA0 = fmaf(ewA, xA0, oA0);
      oB0 = fmaf(ewB, xB0, oB0);
      oA1 = fmaf(ewA, xA1, oA1);
      oB1 = fmaf(ewB, xB1, oB1);
      oA2 = fmaf(ewA, xA2, oA2);
      oB2 = fmaf(ewB, xB2, oB2);
      oA3 = fmaf(ewA, xA3, oA3);
      oB3 = fmaf(ewB, xB3, oB3);
    }
    if (i < e0) {  // odd tail -> stream A
      const int tg = __builtin_amdgcn_readfirstlane(csr[i]);
      const ushort4 cx = *(const ushort4*)(xbf + (size_t)tg * 64 + lo * 4);
      const float x0 = bf2f(cx.x), x1 = bf2f(cx.y), x2 = bf2f(cx.z),
                  x3 = bf2f(cx.w);
      float d = y0 * x0;
      d = fmaf(y1, x1, d);
      d = fmaf(y2, x2, d);
      d = fmaf(y3, x3, d);
#pragma unroll
      for (int dd = 1; dd < 16; dd <<= 1) d += __shfl_xor(d, dd);
      const float ew = __builtin_amdgcn_exp2f(fmaf(d, c2, ac2));
      denA += ew;
      oA0 = fmaf(ew, x0, oA0);
      oA1 = fmaf(ew, x1, oA1);
      oA2 = fmaf(ew, x2, oA2);
      oA3 = fmaf(ew, x3, oA3);
    }
    const float inv = 1.f / (denA + denB + 1e-10f);
    ushort4 ou;
    ou.x = f2bf((oA0 + oB0) * inv);
    ou.y = f2bf((oA1 + oB1) * inv);
    ou.z = f2bf((oA2 + oB2) * inv);
    ou.w = f2bf((oA3 + oB3) * inv);
    *(ushort4*)&ys[idx][l * 4] = ou;  // own row: wave-private
  }

  // ---- prefetch gT B-frags (independent of Phase B results) ----
  bf16x8 gb[8];
#pragma unroll
  for (int ks = 0; ks < 8; ++ks) {
    gb[ks] = *(const bf16x8*)(gT + (size_t)(w * 16 + lo) * 1024 + r * 256 +
                              ks * 32 + hi * 8);
  }
  __syncthreads();  // loads in flight during straggler wait

  // ---- Phase C: wave w -> cols w*16..+15 of all 32 rows, K=256 ----
  f32x4 acc0 = {0.f, 0.f, 0.f, 0.f};
  f32x4 acc1 = {0.f, 0.f, 0.f, 0.f};
#pragma unroll
  for (int ks = 0; ks < 8; ++ks) {
    const bf16x8 aA = *(const bf16x8*)&ys[lo][ks * 32 + hi * 8];
    const bf16x8 aB = *(const bf16x8*)&ys[16 + lo][ks * 32 + hi * 8];
    acc0 = __builtin_amdgcn_mfma_f32_16x16x32_bf16(aA, gb[ks], acc0, 0, 0, 0);
    acc1 = __builtin_amdgcn_mfma_f32_16x16x32_bf16(aB, gb[ks], acc1, 0, 0, 0);
  }
#pragma unroll
  for (int i = 0; i < 4; ++i) {
    partial[((size_t)r * NN + m0 + hi * 4 + i) * 64 + w * 16 + lo] = acc0[i];
    partial[((size_t)r * NN + m0 + 16 + hi * 4 + i) * 64 + w * 16 + lo] =
        acc1[i];
  }
}

// ---------------------------------------------------------------------------
// Final per-layer LN: sum 4 relation partials + cvec-mask + bias + residual,
// LayerNorm, write xout (+ bf16). grid 1250, block 256 = 4 waves x 4 nodes.
__global__ __launch_bounds__(256) void ln_kernel(
    const float* __restrict__ partial, const float* __restrict__ xin,
    const float* __restrict__ bp, const float* __restrict__ g,
    const float* __restrict__ b, const int* __restrict__ offs4,
    const float* __restrict__ cvec_l, float* __restrict__ xout,
    ushort* __restrict__ xbf_out) {
  const int t = threadIdx.x;
  const int w = t >> 6, l = t & 63;
  const int m0 = blockIdx.x * 16;
#pragma unroll
  for (int k = 0; k < 4; ++k) {
    const int n = m0 + w * 4 + k;
    float v = partial[((size_t)0 * NN + n) * 64 + l] +
              partial[((size_t)1 * NN + n) * 64 + l] +
              partial[((size_t)2 * NN + n) * 64 + l] +
              partial[((size_t)3 * NN + n) * 64 + l];
#pragma unroll
    for (int r = 0; r < 4; ++r) {
      const bool nz = offs4[r * (NN + 1) + n + 1] > offs4[r * (NN + 1) + n];
      v += nz ? cvec_l[r * 64 + l] : 0.f;
    }
    const float y = v + bp[l] + xin[(size_t)n * 64 + l];
    float s = y, s2 = y * y;
#pragma unroll
    for (int dd = 1; dd < 64; dd <<= 1) {
      s += __shfl_xor(s, dd);
      s2 += __shfl_xor(s2, dd);
    }
    const float mu = s * (1.f / 64.f);
    const float var = s2 * (1.f / 64.f) - mu * mu;
    const float xo = (y - mu) * rsqrtf(var + 1e-5f) * g[l] + b[l];
    xout[(size_t)n * 64 + l] = xo;
    if (xbf_out) xbf_out[(size_t)n * 64 + l] = f2bf(xo);
  }
}

// ---------------------------------------------------------------------------
extern "C" void kernel_launch(void* const* d_in, const int* in_sizes, int n_in,
                              void* d_out, int out_size, void* d_ws,
                              size_t ws_size, hipStream_t stream) {
  const float* feat = (const float*)d_in[1];
  const float* bet = (const float*)d_in[2];
  const float* clo = (const float*)d_in[3];
  const float* nsi = (const float*)d_in[4];
  const int* esrc = (const int*)d_in[5];
  const int* etgt = (const int*)d_in[6];
  const float* Wf = (const float*)d_in[7];
  const float* bf = (const float*)d_in[8];
  const float* Wc = (const float*)d_in[9];
  const float* bc = (const float*)d_in[10];
  const float* Wq = (const float*)d_in[11];
  const float* bq = (const float*)d_in[12];
  const float* Wk = (const float*)d_in[13];
  const float* bk = (const float*)d_in[14];
  const float* Wv = (const float*)d_in[15];
  const float* bv = (const float*)d_in[16];
  const float* Wp = (const float*)d_in[17];
  const float* bp = (const float*)d_in[18];
  const float* sw = (const float*)d_in[19];
  const float* lng = (const float*)d_in[20];
  const float* lnb = (const float*)d_in[21];
  float* out = (float*)d_out;

  char* base = (char*)d_ws;
  size_t off = 0;
  auto alloc = [&](size_t bytes) {
    void* p = base + off;
    off += (bytes + 255) & ~(size_t)255;
    return p;
  };
  float* xa = (float*)alloc((size_t)NN * DD * 4);     // 5.12 MB
  float* xb = (float*)alloc((size_t)NN * DD * 4);     // 5.12 MB
  ushort* xbf = (ushort*)alloc((size_t)NN * DD * 2);  // 2.56 MB
  float* partial = (float*)alloc((size_t)RR * NN * 64 * 4);     // 20.48 MB
  ushort* mT = (ushort*)alloc((size_t)LL * RR * 272 * 64 * 2);  // 557 KB
  ushort* gT = (ushort*)alloc((size_t)LL * 64 * 1024 * 2);      // 262 KB
  float* cvec = (float*)alloc((size_t)LL * RR * 64 * 4);        // 2 KB
  float* gam = (float*)alloc((size_t)LL * RR * HH * 4);         // 128 B
  int* counts = (int*)alloc((size_t)RR * NN * 4);
  int* offsb = (int*)alloc((size_t)RR * (NN + 1) * 4);
  int* csr = (int*)alloc((size_t)RR * EE * 4);
  (void)ws_size;

  // ---- counts zero, then fused encoder+prep+hist ----
  hipMemsetAsync(counts, 0, (size_t)RR * NN * 4, stream);
  hipLaunchKernelGGL(enc_prep_kernel, dim3(6059 + (RR * EE + 255) / 256),
                     dim3(256), 0, stream, feat, bet, clo, Wf, bf, Wc, bc, xa,
                     xbf, Wq, bq, Wk, bk, Wv, bv, Wp, mT, gT, cvec, gam, esrc,
                     counts);
  // ---- scan (also zeroes counts -> cursor), fill ----
  hipLaunchKernelGGL(scan_kernel, dim3(RR), dim3(1024), 0, stream, counts,
                     offsb);
  {
    dim3 gg((EE + 255) / 256, RR);
    hipLaunchKernelGGL(fill_kernel, gg, dim3(256), 0, stream, esrc, etgt, offsb,
                       counts, csr);
  }

  for (int l = 0; l < LL; ++l) {
    const float* xin = (l == 0) ? xa : xb;
    float* xout = (l == LL - 1) ? out : xb;
    ushort* xbf_next = (l == LL - 1) ? (ushort*)nullptr : xbf;
    hipLaunchKernelGGL(yattn_kernel, dim3(NN / 32, RR), dim3(256), 0, stream,
                       xbf, offsb, csr, nsi, sw + l * HH * RR, gam + l * 16,
                       mT + (size_t)l * RR * 17408, gT + (size_t)l * 65536,
                       partial);
    hipLaunchKernelGGL(ln_kernel, dim3(NN / 16), dim3(256), 0, stream, partial,
                       xin, bp + l * 64, lng + l * 64, lnb + l * 64, offsb,
                       cvec + l * 256, xout, xbf_next);
  }
}

// Round 17
// 265.048 us; speedup vs baseline: 1.3760x; 1.0029x over previous
//
#include <hip/hip_runtime.h>
#include <math.h>

#define NN 20000
#define EE 100000
#define RR 4
#define HH 4
#define DD 64
#define FF 128
#define LL 2

typedef __attribute__((ext_vector_type(8))) short bf16x8;
typedef __attribute__((ext_vector_type(4))) float f32x4;

__device__ __forceinline__ ushort f2bf(float f) {
  uint u = __float_as_uint(f);
  u += 0x7FFFu + ((u >> 16) & 1u);
  return (ushort)(u >> 16);
}
__device__ __forceinline__ float bf2f(ushort h) {
  return __uint_as_float((uint)h << 16);
}

// ---------------------------------------------------------------------------
// Fused encoder + weight-prep + edge histogram.
// Blocks [0,5000): encoder; [5000,6059): prep; [6059,...): hist.
__global__ __launch_bounds__(256) void enc_prep_kernel(
    const float* __restrict__ feat, const float* __restrict__ bet,
    const float* __restrict__ clo, const float* __restrict__ Wf,
    const float* __restrict__ bf, const float* __restrict__ Wc,
    const float* __restrict__ bc, float* __restrict__ x,
    ushort* __restrict__ xbf, const float* __restrict__ Wq,
    const float* __restrict__ bq, const float* __restrict__ Wk,
    const float* __restrict__ bk, const float* __restrict__ Wv,
    const float* __restrict__ bv, const float* __restrict__ Wp,
    ushort* __restrict__ mT, ushort* __restrict__ gT, float* __restrict__ cvec,
    float* __restrict__ gam, const int* __restrict__ esrc,
    int* __restrict__ counts) {
  const int t = threadIdx.x;
  if (blockIdx.x >= 6059) {  // ---- hist ----
    const int gid = (blockIdx.x - 6059) * 256 + t;
    if (gid < RR * EE) {
      const int r = gid / EE;
      atomicAdd(&counts[r * NN + esrc[gid]], 1);
    }
    return;
  }
  if (blockIdx.x < 5000) {  // ---- encoder ----
    __shared__ float fs[4][FF];
    const int n0 = blockIdx.x * 4;
    for (int idx = t; idx < 4 * FF; idx += 256) {
      const int rr = idx >> 7, cc = idx & 127;
      const int n = n0 + rr;
      fs[rr][cc] = (n < NN) ? feat[(size_t)n * FF + cc] : 0.f;
    }
    __syncthreads();
    const int g = t >> 6, d = t & 63;
    const int n = n0 + g;
    if (n >= NN) return;
    float acc = bf[d] + bc[d] + bet[n] * Wc[d] + clo[n] * Wc[DD + d];
#pragma unroll 8
    for (int f = 0; f < FF; ++f) acc = fmaf(fs[g][f], Wf[f * DD + d], acc);
    x[(size_t)n * DD + d] = acc;
    xbf[(size_t)n * DD + d] = f2bf(acc);
    return;
  }
  const int idx = (blockIdx.x - 5000) * 256 + t;
  const int R1 = LL * RR * 272 * 64;  // 139264
  const int R2 = LL * 64 * 1024;      // 131072
  if (idx < R1) {
    const int lr = idx / (272 * 64);
    const int rem = idx % (272 * 64);
    const int col = rem >> 6, i = rem & 63;
    const float* wq = Wq + (size_t)lr * 64 * 256;
    const float* wk = Wk + (size_t)lr * 64 * 256;
    float v = 0.f;
    if (col < 256) {
      const int h = col >> 6, j = col & 63;
      const float* qa = wq + (size_t)i * 256 + h * 64;
      const float* kb = wk + (size_t)j * 256 + h * 64;
#pragma unroll 8
      for (int d = 0; d < 64; ++d) v = fmaf(qa[d], kb[d], v);
    } else if (col < 260) {
      const int h = col - 256;
      const float* qa = wq + (size_t)i * 256 + h * 64;
      const float* bb = bk + lr * 256 + h * 64;
#pragma unroll 8
      for (int d = 0; d < 64; ++d) v = fmaf(qa[d], bb[d], v);
    } else if (col < 264) {
      const int h = col - 260;
      const float* ka = wk + (size_t)i * 256 + h * 64;
      const float* bb = bq + lr * 256 + h * 64;
#pragma unroll 8
      for (int d = 0; d < 64; ++d) v = fmaf(ka[d], bb[d], v);
    }
    mT[idx] = f2bf(v);
  } else if (idx < R1 + R2) {
    const int id = idx - R1;  // = l*65536 + j*1024 + k
    const int lj = id >> 10;
    const int k = id & 1023;
    const int l = lj >> 6, j = lj & 63;
    const int r = k >> 8, h = (k >> 6) & 3, v_ = k & 63;
    const float* wv =
        Wv + (size_t)(l * RR + r) * 64 * 256 + (size_t)v_ * 256 + h * 64;
    const float* wp =
        Wp + (size_t)l * 65536 + (size_t)(r * 256 + h * 64) * 64 + j;
    float s = 0.f;
#pragma unroll 8
    for (int d = 0; d < 64; ++d) s = fmaf(wv[d], wp[d * 64], s);
    gT[id] = f2bf(s);
  } else if (idx < R1 + R2 + 512) {
    const int id = idx - R1 - R2;  // = l*256 + r*64 + j
    const int l = id >> 8, rj = id & 255;
    const int r = rj >> 6, j = rj & 63;
    const float* bb = bv + (l * RR + r) * 256;
    const float* wp = Wp + (size_t)l * 65536 + (size_t)(r * 256) * 64 + j;
    float s = 0.f;
    for (int q2 = 0; q2 < 256; ++q2) s = fmaf(bb[q2], wp[q2 * 64], s);
    cvec[id] = s;
  } else if (idx < R1 + R2 + 512 + 32) {
    const int id = idx - R1 - R2 - 512;  // = lr*4 + h
    const int lr = id >> 2, h = id & 3;
    const float* a = bq + lr * 256 + h * 64;
    const float* b2 = bk + lr * 256 + h * 64;
    float s = 0.f;
    for (int d = 0; d < 64; ++d) s = fmaf(a[d], b2[d], s);
    gam[id] = s;
  }
}

// ---------------------------------------------------------------------------
// Exclusive scan (1 block/relation, 1024 x 20); also zeroes counts -> cursor.
__global__ __launch_bounds__(1024) void scan_kernel(
    int* __restrict__ counts, int* __restrict__ offs) {
  __shared__ int ts[1024];
  const int r = blockIdx.x, t = threadIdx.x;
  const int base = t * 20;
  int loc[20];
  int run = 0;
#pragma unroll
  for (int k = 0; k < 20; ++k) {
    const int i = base + k;
    const int v = (i < NN) ? counts[r * NN + i] : 0;
    if (i < NN) counts[r * NN + i] = 0;  // becomes fill cursor
    run += v;
    loc[k] = run;
  }
  ts[t] = run;
  __syncthreads();
#pragma unroll
  for (int s = 1; s < 1024; s <<= 1) {
    const int add = (t >= s) ? ts[t - s] : 0;
    __syncthreads();
    ts[t] += add;
    __syncthreads();
  }
  const int prev = (t == 0) ? 0 : ts[t - 1];
#pragma unroll
  for (int k = 0; k < 20; ++k) {
    const int i = base + k;
    if (i < NN) offs[r * (NN + 1) + i + 1] = prev + loc[k];
  }
  if (t == 0) offs[r * (NN + 1)] = 0;
}

__global__ __launch_bounds__(256) void fill_kernel(
    const int* __restrict__ esrc, const int* __restrict__ etgt,
    const int* __restrict__ offs, int* __restrict__ cursor,
    int* __restrict__ csr) {
  const int e = blockIdx.x * 256 + threadIdx.x;
  const int r = blockIdx.y;
  if (e < EE) {
    const int s = esrc[(size_t)r * EE + e];
    const int pos = offs[r * (NN + 1) + s] + atomicAdd(&cursor[r * NN + s], 1);
    csr[(size_t)r * EE + pos] = etgt[(size_t)r * EE + e];
  }
}

// ---------------------------------------------------------------------------
// FUSED Y-GEMM + attention + projection. grid (625, 4) = (32-node tile, rel).
// block 256 = 4 waves.
// Phase A (one barrier): Y'[32][256] = x_tile @ M_r + wbeta; wave 3 also
//          computes alpha[32][4].
// Phase B (wave-private): wave w handles 8 nodes; QUAD-stream edge loop
//          (4 gathers in flight; max-free softmax merges by plain addition);
//          attr row overwrites own Y row in LDS.
// Phase C: gT B-frags prefetched before the barrier; wave w projects cols
//          w*16..+15 of all 32 rows (K=256); writes bf16 partial[r][n][64].
__global__ __launch_bounds__(256) void yattn_kernel(
    const ushort* __restrict__ xbf, const int* __restrict__ offs4,
    const int* __restrict__ csr4, const float* __restrict__ nsi,
    const float* __restrict__ sw_l, const float* __restrict__ gam_l,
    const ushort* __restrict__ mT_l, const ushort* __restrict__ gT,
    ushort* __restrict__ partial) {
  __shared__ ushort ys[32][264];  // 16.9 KB
  __shared__ float alph[32][4];
  const int t = threadIdx.x;
  const int w = t >> 6, l = t & 63;
  const int hi = l >> 4, lo = l & 15;
  const int h = hi;
  const int m0 = blockIdx.x * 32;
  const int r = blockIdx.y;
  const ushort* mTr = mT_l + (size_t)r * 17408;  // [272][64]

  // ---- Phase A: two 16-row groups ----
  const ushort* arow0 = xbf + (size_t)(m0 + lo) * 64 + hi * 8;
  const ushort* arow1 = xbf + (size_t)(m0 + 16 + lo) * 64 + hi * 8;
  const bf16x8 a00 = *(const bf16x8*)(arow0);
  const bf16x8 a01 = *(const bf16x8*)(arow0 + 32);
  const bf16x8 a10 = *(const bf16x8*)(arow1);
  const bf16x8 a11 = *(const bf16x8*)(arow1 + 32);
#pragma unroll
  for (int nt = 0; nt < 4; ++nt) {
    const int col0 = w * 64 + nt * 16;
    const ushort* brow = mTr + (size_t)(col0 + lo) * 64 + hi * 8;
    const bf16x8 b0 = *(const bf16x8*)(brow);
    const bf16x8 b1 = *(const bf16x8*)(brow + 32);
    f32x4 z0 = {0.f, 0.f, 0.f, 0.f};
    z0 = __builtin_amdgcn_mfma_f32_16x16x32_bf16(a00, b0, z0, 0, 0, 0);
    z0 = __builtin_amdgcn_mfma_f32_16x16x32_bf16(a01, b1, z0, 0, 0, 0);
    f32x4 z1 = {0.f, 0.f, 0.f, 0.f};
    z1 = __builtin_amdgcn_mfma_f32_16x16x32_bf16(a10, b0, z1, 0, 0, 0);
    z1 = __builtin_amdgcn_mfma_f32_16x16x32_bf16(a11, b1, z1, 0, 0, 0);
    const int col = col0 + lo;
    const float wb = bf2f(mTr[(size_t)(260 + (col >> 6)) * 64 + (col & 63)]);
#pragma unroll
    for (int i = 0; i < 4; ++i) {
      ys[hi * 4 + i][col] = f2bf(z0[i] + wb);
      ys[16 + hi * 4 + i][col] = f2bf(z1[i] + wb);
    }
  }
  if (w == 3) {  // alpha tiles: walpha rows 256..259 of mT
    const ushort* brow = mTr + (size_t)(256 + lo) * 64 + hi * 8;
    const bf16x8 b0 = *(const bf16x8*)(brow);
    const bf16x8 b1 = *(const bf16x8*)(brow + 32);
    f32x4 z0 = {0.f, 0.f, 0.f, 0.f};
    z0 = __builtin_amdgcn_mfma_f32_16x16x32_bf16(a00, b0, z0, 0, 0, 0);
    z0 = __builtin_amdgcn_mfma_f32_16x16x32_bf16(a01, b1, z0, 0, 0, 0);
    f32x4 z1 = {0.f, 0.f, 0.f, 0.f};
    z1 = __builtin_amdgcn_mfma_f32_16x16x32_bf16(a10, b0, z1, 0, 0, 0);
    z1 = __builtin_amdgcn_mfma_f32_16x16x32_bf16(a11, b1, z1, 0, 0, 0);
    if (lo < 4) {
#pragma unroll
      for (int i = 0; i < 4; ++i) {
        alph[hi * 4 + i][lo] = z0[i];
        alph[16 + hi * 4 + i][lo] = z1[i];
      }
    }
  }
  __syncthreads();

  // ---- Phase B: 8 nodes per wave, quad-stream gathers ----
  const int* offs = offs4 + r * (NN + 1);
  const int* csr = csr4 + (size_t)r * EE;
  const float swh = sw_l[h * RR + r];
  const float gamh = gam_l[r * 4 + h];
  for (int k = 0; k < 8; ++k) {
    const int idx = w * 8 + k;
    const int n = m0 + idx;
    const ushort4 yu = *(const ushort4*)&ys[idx][l * 4];
    const float y0 = bf2f(yu.x), y1 = bf2f(yu.y), y2 = bf2f(yu.z),
                y3 = bf2f(yu.w);
    const float c2 = 0.18033688f * nsi[n] * swh;
    const float ac2 = (alph[idx][h] + gamh) * c2;
    const int s0 = offs[n], e0 = offs[n + 1];
    float denA = 0.f, oA0 = 0.f, oA1 = 0.f, oA2 = 0.f, oA3 = 0.f;
    float denB = 0.f, oB0 = 0.f, oB1 = 0.f, oB2 = 0.f, oB3 = 0.f;
    int i = s0;
    for (; i + 3 < e0; i += 4) {  // quad stream
      const int tg0 = __builtin_amdgcn_readfirstlane(csr[i]);
      const int tg1 = __builtin_amdgcn_readfirstlane(csr[i + 1]);
      const int tg2 = __builtin_amdgcn_readfirstlane(csr[i + 2]);
      const int tg3 = __builtin_amdgcn_readfirstlane(csr[i + 3]);
      const ushort4 cx0 = *(const ushort4*)(xbf + (size_t)tg0 * 64 + lo * 4);
      const ushort4 cx1 = *(const ushort4*)(xbf + (size_t)tg1 * 64 + lo * 4);
      const ushort4 cx2 = *(const ushort4*)(xbf + (size_t)tg2 * 64 + lo * 4);
      const ushort4 cx3 = *(const ushort4*)(xbf + (size_t)tg3 * 64 + lo * 4);
      const float x00 = bf2f(cx0.x), x01 = bf2f(cx0.y), x02 = bf2f(cx0.z),
                  x03 = bf2f(cx0.w);
      const float x10 = bf2f(cx1.x), x11 = bf2f(cx1.y), x12 = bf2f(cx1.z),
                  x13 = bf2f(cx1.w);
      const float x20 = bf2f(cx2.x), x21 = bf2f(cx2.y), x22 = bf2f(cx2.z),
                  x23 = bf2f(cx2.w);
      const float x30 = bf2f(cx3.x), x31 = bf2f(cx3.y), x32 = bf2f(cx3.z),
                  x33 = bf2f(cx3.w);
      float d0 = y0 * x00, d1 = y0 * x10, d2 = y0 * x20, d3 = y0 * x30;
      d0 = fmaf(y1, x01, d0);
      d1 = fmaf(y1, x11, d1);
      d2 = fmaf(y1, x21, d2);
      d3 = fmaf(y1, x31, d3);
      d0 = fmaf(y2, x02, d0);
      d1 = fmaf(y2, x12, d1);
      d2 = fmaf(y2, x22, d2);
      d3 = fmaf(y2, x32, d3);
      d0 = fmaf(y3, x03, d0);
      d1 = fmaf(y3, x13, d1);
      d2 = fmaf(y3, x23, d2);
      d3 = fmaf(y3, x33, d3);
#pragma unroll
      for (int dd = 1; dd < 16; dd <<= 1) {
        d0 += __shfl_xor(d0, dd);
        d1 += __shfl_xor(d1, dd);
        d2 += __shfl_xor(d2, dd);
        d3 += __shfl_xor(d3, dd);
      }
      const float e0w = __builtin_amdgcn_exp2f(fmaf(d0, c2, ac2));
      const float e1w = __builtin_amdgcn_exp2f(fmaf(d1, c2, ac2));
      const float e2w = __builtin_amdgcn_exp2f(fmaf(d2, c2, ac2));
      const float e3w = __builtin_amdgcn_exp2f(fmaf(d3, c2, ac2));
      denA += e0w + e2w;
      denB += e1w + e3w;
      oA0 = fmaf(e0w, x00, oA0);
      oB0 = fmaf(e1w, x10, oB0);
      oA0 = fmaf(e2w, x20, oA0);
      oB0 = fmaf(e3w, x30, oB0);
      oA1 = fmaf(e0w, x01, oA1);
      oB1 = fmaf(e1w, x11, oB1);
      oA1 = fmaf(e2w, x21, oA1);
      oB1 = fmaf(e3w, x31, oB1);
      oA2 = fmaf(e0w, x02, oA2);
      oB2 = fmaf(e1w, x12, oB2);
      oA2 = fmaf(e2w, x22, oA2);
      oB2 = fmaf(e3w, x32, oB2);
      oA3 = fmaf(e0w, x03, oA3);
      oB3 = fmaf(e1w, x13, oB3);
      oA3 = fmaf(e2w, x23, oA3);
      oB3 = fmaf(e3w, x33, oB3);
    }
    for (; i < e0; ++i) {  // tail
      const int tg = __builtin_amdgcn_readfirstlane(csr[i]);
      const ushort4 cx = *(const ushort4*)(xbf + (size_t)tg * 64 + lo * 4);
      const float x0 = bf2f(cx.x), x1 = bf2f(cx.y), x2 = bf2f(cx.z),
                  x3 = bf2f(cx.w);
      float d = y0 * x0;
      d = fmaf(y1, x1, d);
      d = fmaf(y2, x2, d);
      d = fmaf(y3, x3, d);
#pragma unroll
      for (int dd = 1; dd < 16; dd <<= 1) d += __shfl_xor(d, dd);
      const float ew = __builtin_amdgcn_exp2f(fmaf(d, c2, ac2));
      denA += ew;
      oA0 = fmaf(ew, x0, oA0);
      oA1 = fmaf(ew, x1, oA1);
      oA2 = fmaf(ew, x2, oA2);
      oA3 = fmaf(ew, x3, oA3);
    }
    const float inv = 1.f / (denA + denB + 1e-10f);
    ushort4 ou;
    ou.x = f2bf((oA0 + oB0) * inv);
    ou.y = f2bf((oA1 + oB1) * inv);
    ou.z = f2bf((oA2 + oB2) * inv);
    ou.w = f2bf((oA3 + oB3) * inv);
    *(ushort4*)&ys[idx][l * 4] = ou;  // own row: wave-private
  }

  // ---- prefetch gT B-frags (independent of Phase B results) ----
  bf16x8 gb[8];
#pragma unroll
  for (int ks = 0; ks < 8; ++ks) {
    gb[ks] = *(const bf16x8*)(gT + (size_t)(w * 16 + lo) * 1024 + r * 256 +
                              ks * 32 + hi * 8);
  }
  __syncthreads();  // loads in flight during straggler wait

  // ---- Phase C: wave w -> cols w*16..+15 of all 32 rows, K=256 ----
  f32x4 acc0 = {0.f, 0.f, 0.f, 0.f};
  f32x4 acc1 = {0.f, 0.f, 0.f, 0.f};
#pragma unroll
  for (int ks = 0; ks < 8; ++ks) {
    const bf16x8 aA = *(const bf16x8*)&ys[lo][ks * 32 + hi * 8];
    const bf16x8 aB = *(const bf16x8*)&ys[16 + lo][ks * 32 + hi * 8];
    acc0 = __builtin_amdgcn_mfma_f32_16x16x32_bf16(aA, gb[ks], acc0, 0, 0, 0);
    acc1 = __builtin_amdgcn_mfma_f32_16x16x32_bf16(aB, gb[ks], acc1, 0, 0, 0);
  }
#pragma unroll
  for (int i = 0; i < 4; ++i) {
    partial[((size_t)r * NN + m0 + hi * 4 + i) * 64 + w * 16 + lo] =
        f2bf(acc0[i]);
    partial[((size_t)r * NN + m0 + 16 + hi * 4 + i) * 64 + w * 16 + lo] =
        f2bf(acc1[i]);
  }
}

// ---------------------------------------------------------------------------
// Final per-layer LN: sum 4 relation partials (bf16) + cvec-mask + bias +
// residual, LayerNorm, write xout (+ bf16). grid 1250, block 256.
__global__ __launch_bounds__(256) void ln_kernel(
    const ushort* __restrict__ partial, const float* __restrict__ xin,
    const float* __restrict__ bp, const float* __restrict__ g,
    const float* __restrict__ b, const int* __restrict__ offs4,
    const float* __restrict__ cvec_l, float* __restrict__ xout,
    ushort* __restrict__ xbf_out) {
  const int t = threadIdx.x;
  const int w = t >> 6, l = t & 63;
  const int m0 = blockIdx.x * 16;
#pragma unroll
  for (int k = 0; k < 4; ++k) {
    const int n = m0 + w * 4 + k;
    float v = bf2f(partial[((size_t)0 * NN + n) * 64 + l]) +
              bf2f(partial[((size_t)1 * NN + n) * 64 + l]) +
              bf2f(partial[((size_t)2 * NN + n) * 64 + l]) +
              bf2f(partial[((size_t)3 * NN + n) * 64 + l]);
#pragma unroll
    for (int r = 0; r < 4; ++r) {
      const bool nz = offs4[r * (NN + 1) + n + 1] > offs4[r * (NN + 1) + n];
      v += nz ? cvec_l[r * 64 + l] : 0.f;
    }
    const float y = v + bp[l] + xin[(size_t)n * 64 + l];
    float s = y, s2 = y * y;
#pragma unroll
    for (int dd = 1; dd < 64; dd <<= 1) {
      s += __shfl_xor(s, dd);
      s2 += __shfl_xor(s2, dd);
    }
    const float mu = s * (1.f / 64.f);
    const float var = s2 * (1.f / 64.f) - mu * mu;
    const float xo = (y - mu) * rsqrtf(var + 1e-5f) * g[l] + b[l];
    xout[(size_t)n * 64 + l] = xo;
    if (xbf_out) xbf_out[(size_t)n * 64 + l] = f2bf(xo);
  }
}

// ---------------------------------------------------------------------------
extern "C" void kernel_launch(void* const* d_in, const int* in_sizes, int n_in,
                              void* d_out, int out_size, void* d_ws,
                              size_t ws_size, hipStream_t stream) {
  const float* feat = (const float*)d_in[1];
  const float* bet = (const float*)d_in[2];
  const float* clo = (const float*)d_in[3];
  const float* nsi = (const float*)d_in[4];
  const int* esrc = (const int*)d_in[5];
  const int* etgt = (const int*)d_in[6];
  const float* Wf = (const float*)d_in[7];
  const float* bf = (const float*)d_in[8];
  const float* Wc = (const float*)d_in[9];
  const float* bc = (const float*)d_in[10];
  const float* Wq = (const float*)d_in[11];
  const float* bq = (const float*)d_in[12];
  const float* Wk = (const float*)d_in[13];
  const float* bk = (const float*)d_in[14];
  const float* Wv = (const float*)d_in[15];
  const float* bv = (const float*)d_in[16];
  const float* Wp = (const float*)d_in[17];
  const float* bp = (const float*)d_in[18];
  const float* sw = (const float*)d_in[19];
  const float* lng = (const float*)d_in[20];
  const float* lnb = (const float*)d_in[21];
  float* out = (float*)d_out;

  char* base = (char*)d_ws;
  size_t off = 0;
  auto alloc = [&](size_t bytes) {
    void* p = base + off;
    off += (bytes + 255) & ~(size_t)255;
    return p;
  };
  float* xa = (float*)alloc((size_t)NN * DD * 4);     // 5.12 MB
  float* xb = (float*)alloc((size_t)NN * DD * 4);     // 5.12 MB
  ushort* xbf = (ushort*)alloc((size_t)NN * DD * 2);  // 2.56 MB
  ushort* partial = (ushort*)alloc((size_t)RR * NN * 64 * 2);   // 10.24 MB
  ushort* mT = (ushort*)alloc((size_t)LL * RR * 272 * 64 * 2);  // 557 KB
  ushort* gT = (ushort*)alloc((size_t)LL * 64 * 1024 * 2);      // 262 KB
  float* cvec = (float*)alloc((size_t)LL * RR * 64 * 4);        // 2 KB
  float* gam = (float*)alloc((size_t)LL * RR * HH * 4);         // 128 B
  int* counts = (int*)alloc((size_t)RR * NN * 4);
  int* offsb = (int*)alloc((size_t)RR * (NN + 1) * 4);
  int* csr = (int*)alloc((size_t)RR * EE * 4);
  (void)ws_size;

  // ---- counts zero, then fused encoder+prep+hist ----
  hipMemsetAsync(counts, 0, (size_t)RR * NN * 4, stream);
  hipLaunchKernelGGL(enc_prep_kernel, dim3(6059 + (RR * EE + 255) / 256),
                     dim3(256), 0, stream, feat, bet, clo, Wf, bf, Wc, bc, xa,
                     xbf, Wq, bq, Wk, bk, Wv, bv, Wp, mT, gT, cvec, gam, esrc,
                     counts);
  // ---- scan (also zeroes counts -> cursor), fill ----
  hipLaunchKernelGGL(scan_kernel, dim3(RR), dim3(1024), 0, stream, counts,
                     offsb);
  {
    dim3 gg((EE + 255) / 256, RR);
    hipLaunchKernelGGL(fill_kernel, gg, dim3(256), 0, stream, esrc, etgt, offsb,
                       counts, csr);
  }

  for (int l = 0; l < LL; ++l) {
    const float* xin = (l == 0) ? xa : xb;
    float* xout = (l == LL - 1) ? out : xb;
    ushort* xbf_next = (l == LL - 1) ? (ushort*)nullptr : xbf;
    hipLaunchKernelGGL(yattn_kernel, dim3(NN / 32, RR), dim3(256), 0, stream,
                       xbf, offsb, csr, nsi, sw + l * HH * RR, gam + l * 16,
                       mT + (size_t)l * RR * 17408, gT + (size_t)l * 65536,
                       partial);
    hipLaunchKernelGGL(ln_kernel, dim3(NN / 16), dim3(256), 0, stream, partial,
                       xin, bp + l * 64, lng + l * 64, lnb + l * 64, offsb,
                       cvec + l * 256, xout, xbf_next);
  }
}